// Round 5
// baseline (400.331 us; speedup 1.0000x reference)
//
#include <hip/hip_runtime.h>

// LSTMNet: SEQ=600, B=4096, IN=6, H=30, OUT=61, fp32.
// Layout A2 + opaque-asm weight loads + 4 waves/SIMD.
//   One wave = one batch element. lane = 32*half + u.
//   half 0, u<30: gate rows i,f     half 1, u<30: gate rows g,o
// Weight state: 36 f32x2 = 72 VGPRs/lane -> total ~120 VGPRs, fits the
// 128-reg budget at 4 waves/SIMD, so the allocator keeps the asm-loaded
// weights in ARCH VGPRs (rounds 1-4 failure: AGPR spill + per-use
// v_accvgpr_read because v_pk_fma_f32 cannot read AGPRs).
// h broadcast via one 32-float LDS row; cross-half exchange via shfl_xor(32).

#define SEQ   600
#define BATCH 4096
#define INP   6
#define HID   30
#define NOUT  61

typedef float f32x2 __attribute__((ext_vector_type(2)));

__device__ __forceinline__ float rcp_(float x)  { return __builtin_amdgcn_rcpf(x); }
__device__ __forceinline__ float exp2_(float x) { return __builtin_amdgcn_exp2f(x); }
#define LOG2E  1.4426950408889634f
#define LOG2E2 2.8853900817779268f

extern "C" __global__ void __launch_bounds__(64, 4)
lstm_fused5(const float* __restrict__ X,   const float* __restrict__ Wih,
            const float* __restrict__ Whh, const float* __restrict__ bih,
            const float* __restrict__ bhh, const float* __restrict__ W1,
            const float* __restrict__ b1,  const float* __restrict__ W2,
            const float* __restrict__ b2,  float* __restrict__ out)
{
    __shared__ float h_sh[32];    // h row for this wave's element (pads stay 0)
    __shared__ float o1_sh[32];   // fc1 activations

    const int lane = threadIdx.x;          // 0..63
    const int u    = lane & 31;            // hidden unit (active u < 30)
    const int half = lane >> 5;            // 0: gates (i,f); 1: gates (g,o)
    const int uu   = (u < HID) ? u : (HID - 1);   // clamped for safe addresses
    const int b    = blockIdx.x;           // batch element (one per wave/block)
    const bool act = (u < HID);

    if (lane < 32) h_sh[lane] = 0.0f;

    // ---- opaque weight loads: 2 gate rows x 15 k-pairs, 2 x 3 input pairs ----
    const int rowA = (half ? 2 : 0) * HID + uu;   // i or g
    const int rowB = (half ? 3 : 1) * HID + uu;   // f or o

    const float* ra = Whh + rowA * HID;
    const float* rb = Whh + rowB * HID;
    f32x2 wA[15], wB[15];
    #pragma unroll
    for (int j = 0; j < 15; ++j) {
        asm volatile("global_load_dwordx2 %0, %1, off" : "=v"(wA[j]) : "v"(ra + 2 * j));
        asm volatile("global_load_dwordx2 %0, %1, off" : "=v"(wB[j]) : "v"(rb + 2 * j));
    }
    const float* sa = Wih + rowA * INP;
    const float* sb = Wih + rowB * INP;
    f32x2 xA[3], xB[3];
    #pragma unroll
    for (int j = 0; j < 3; ++j) {
        asm volatile("global_load_dwordx2 %0, %1, off" : "=v"(xA[j]) : "v"(sa + 2 * j));
        asm volatile("global_load_dwordx2 %0, %1, off" : "=v"(xB[j]) : "v"(sb + 2 * j));
    }
    asm volatile("s_waitcnt vmcnt(0)" ::: "memory");

    float bA = 0.f, bB = 0.f;
    if (act) {
        bA = bih[rowA] + bhh[rowA];
        bB = bih[rowB] + bhh[rowB];
    }
    asm volatile("" : "+v"(bA), "+v"(bB));

    // branchless per-half nonlinearity constants:
    //   half0: nA = sigm(aA);  half1: nA = tanh(aA) = 2*sigm(2aA)-1
    const float mA = half ? -LOG2E2 : -LOG2E;
    const float sA = half ? 2.0f : 1.0f;
    const float cA = half ? -1.0f : 0.0f;

    float c = 0.f, h = 0.f;

    // x: wave-uniform 24B; per-lane VMEM loads (all lanes same line -> 1 fetch)
    f32x2 xc0, xc1, xc2, xn0, xn1, xn2;
    {
        const f32x2* p = (const f32x2*)(X + (size_t)b * INP);   // t = 0
        xc0 = p[0]; xc1 = p[1]; xc2 = p[2];
    }
    asm volatile("s_waitcnt lgkmcnt(0)" ::: "memory");   // h_sh init visible

    const float4* h4p = (const float4*)(&h_sh[0]);
    const f32x2*  h2p = (const f32x2*)(&h_sh[0]);

    for (int t = 0; t < SEQ; ++t) {
        // prefetch x for t+1 (VMEM; drained by compiler just before use)
        const int tn = (t + 1 < SEQ) ? (t + 1) : (SEQ - 1);
        const f32x2* p = (const f32x2*)(X + ((size_t)tn * BATCH + b) * INP);
        xn0 = p[0]; xn1 = p[1]; xn2 = p[2];

        // h: 7x float4 (k0..27) + 1x float2 (k28,29), broadcast to all lanes
        float4 H0 = h4p[0], H1 = h4p[1], H2 = h4p[2], H3 = h4p[3];
        float4 H4 = h4p[4], H5 = h4p[5], H6 = h4p[6];
        f32x2  Ht = h2p[14];

        // two chains per gate for FMA-latency ILP
        f32x2 aAe = f32x2{bA, 0.f}, aAo = (f32x2)0.f;
        f32x2 aBe = f32x2{bB, 0.f}, aBo = (f32x2)0.f;

        #define PK(J, HX, HY, E) do {                                  \
            f32x2 hv = f32x2{HX, HY};                                  \
            aA##E = __builtin_elementwise_fma(wA[J], hv, aA##E);       \
            aB##E = __builtin_elementwise_fma(wB[J], hv, aB##E);       \
        } while (0)
        PK(0,  H0.x, H0.y, e); PK(1,  H0.z, H0.w, o);
        PK(2,  H1.x, H1.y, e); PK(3,  H1.z, H1.w, o);
        PK(4,  H2.x, H2.y, e); PK(5,  H2.z, H2.w, o);
        PK(6,  H3.x, H3.y, e); PK(7,  H3.z, H3.w, o);
        PK(8,  H4.x, H4.y, e); PK(9,  H4.z, H4.w, o);
        PK(10, H5.x, H5.y, e); PK(11, H5.z, H5.w, o);
        PK(12, H6.x, H6.y, e); PK(13, H6.z, H6.w, o);
        aAe = __builtin_elementwise_fma(wA[14], Ht, aAe);
        aBe = __builtin_elementwise_fma(wB[14], Ht, aBe);
        #undef PK
        // input projection
        aAo = __builtin_elementwise_fma(xA[0], xc0, aAo);
        aBo = __builtin_elementwise_fma(xB[0], xc0, aBo);
        aAe = __builtin_elementwise_fma(xA[1], xc1, aAe);
        aBe = __builtin_elementwise_fma(xB[1], xc1, aBe);
        aAo = __builtin_elementwise_fma(xA[2], xc2, aAo);
        aBo = __builtin_elementwise_fma(xB[2], xc2, aBo);

        const f32x2 aAv = aAe + aAo;
        const f32x2 aBv = aBe + aBo;
        const float aA = aAv.x + aAv.y;
        const float aB = aBv.x + aBv.y;

        // half0: nA=sigm_i, nB=sigm_f ; half1: nA=tanh_g, nB=sigm_o
        const float nA = fmaf(sA, rcp_(1.0f + exp2_(mA * aA)), cA);
        const float nB = rcp_(1.0f + exp2_(-LOG2E * aB));

        const float vA = __shfl_xor(nA, 32);
        const float vB = __shfl_xor(nB, 32);

        const float F = half ? vB : nB;   // sigm_f
        const float O = half ? nB : vB;   // sigm_o
        c = fmaf(F, c, nA * vA);          // nA*vA == sigm_i * tanh_g on both halves
        const float tc = 1.0f - 2.0f * rcp_(exp2_(LOG2E2 * c) + 1.0f);
        h = O * tc;

        if (lane < HID) h_sh[lane] = h;   // low half writes h row
        asm volatile("s_waitcnt lgkmcnt(0)" ::: "memory");

        xc0 = xn0; xc1 = xn1; xc2 = xn2;
    }

    // ---- FC1 (lanes 0..29): o1[u] = b1[u] + sum_k W1[u,k] * h[k] ----
    if (lane < HID) {
        float a1 = b1[lane];
        const float* w1r = W1 + lane * HID;
        #pragma unroll
        for (int k = 0; k < HID; ++k) a1 = fmaf(w1r[k], h_sh[k], a1);
        o1_sh[lane] = a1;
    }
    asm volatile("s_waitcnt lgkmcnt(0)" ::: "memory");

    // ---- FC2 (lanes 0..60): out[o] = b2[o] + sum_j W2[o,j] * o1[j] ----
    if (lane < NOUT) {
        float a2 = b2[lane];
        const float* w2r = W2 + lane * HID;
        #pragma unroll
        for (int k = 0; k < HID; ++k) a2 = fmaf(w2r[k], o1_sh[k], a2);
        out[(size_t)b * NOUT + lane] = a2;
    }
}

extern "C" void kernel_launch(void* const* d_in, const int* in_sizes, int n_in,
                              void* d_out, int out_size, void* d_ws, size_t ws_size,
                              hipStream_t stream) {
    const float* X   = (const float*)d_in[0];
    const float* Wih = (const float*)d_in[1];
    const float* Whh = (const float*)d_in[2];
    const float* bih = (const float*)d_in[3];
    const float* bhh = (const float*)d_in[4];
    const float* W1  = (const float*)d_in[5];
    const float* b1  = (const float*)d_in[6];
    const float* W2  = (const float*)d_in[7];
    const float* b2  = (const float*)d_in[8];
    float* out = (float*)d_out;

    dim3 grid(BATCH);   // 4096 single-wave blocks (16 per CU -> 4 waves/SIMD)
    dim3 block(64);
    hipLaunchKernelGGL(lstm_fused5, grid, block, 0, stream,
                       X, Wih, Whh, bih, bhh, W1, b1, W2, b2, out);
}

// Round 7
// 386.739 us; speedup vs baseline: 1.0351x; 1.0351x over previous
//
#include <hip/hip_runtime.h>

// LSTMNet: SEQ=600, B=4096, IN=6, H=30, OUT=61, fp32 in/out.
// Layout A2-f16: one wave = one batch element; lane = 32*half + u.
//   half 0, u<30: gate rows i,f     half 1, u<30: gate rows g,o
// Weights + h stored as f16 pairs, consumed by v_dot2_f32_f16 (f32 accum).
// Weight state: 36 f16x2 = 38 VGPRs/lane -> total pressure ~90, comfortably
// under the 128-reg cap at 4 waves/SIMD, so the allocator keeps everything
// in ARCH VGPRs (rounds 1-5 failure: AGPR live-range split + accvgpr moves
// whenever pressure ~= budget).
// h broadcast via one 32-half LDS row; cross-half exchange via shfl_xor(32).

#define SEQ   600
#define BATCH 4096
#define INP   6
#define HID   30
#define NOUT  61
#define WPB   2   // waves (batch elements) per block

typedef __fp16 f16;                                        // match builtin types
typedef f16  f16x2 __attribute__((ext_vector_type(2)));
typedef float f32x2 __attribute__((ext_vector_type(2)));

__device__ __forceinline__ float rcp_(float x)  { return __builtin_amdgcn_rcpf(x); }
__device__ __forceinline__ float exp2_(float x) { return __builtin_amdgcn_exp2f(x); }
__device__ __forceinline__ f16x2 as_h2(unsigned v) {
    union { unsigned u; f16x2 h; } c; c.u = v; return c.h;
}
#define LOG2E  1.4426950408889634f
#define LOG2E2 2.8853900817779268f

extern "C" __global__ void __launch_bounds__(64 * WPB, 4)
lstm_fused6(const float* __restrict__ X,   const float* __restrict__ Wih,
            const float* __restrict__ Whh, const float* __restrict__ bih,
            const float* __restrict__ bhh, const float* __restrict__ W1,
            const float* __restrict__ b1,  const float* __restrict__ W2,
            const float* __restrict__ b2,  float* __restrict__ out)
{
    __shared__ __align__(16) f16 h_sh[WPB][32];   // h row per element, f16, pads 0
    __shared__ float o1_sh[WPB][32];              // fc1 activations

    const int tid  = threadIdx.x;
    const int lane = tid & 63;
    const int u    = lane & 31;            // hidden unit (active u < 30)
    const int half = lane >> 5;            // 0: gates (i,f); 1: gates (g,o)
    const int e    = tid >> 6;             // wave slot in block
    const int b    = blockIdx.x * WPB + e; // batch element (wave-uniform)
    const int uu   = (u < HID) ? u : (HID - 1);   // clamped for safe addresses
    const bool act = (u < HID);

    if (lane < 32) h_sh[e][lane] = (f16)0.f;

    // ---- weights -> f16x2 registers (RTN casts, one-time) ----
    const int rowA = (half ? 2 : 0) * HID + uu;   // i or g
    const int rowB = (half ? 3 : 1) * HID + uu;   // f or o

    const float* ra = Whh + rowA * HID;
    const float* rb = Whh + rowB * HID;
    f16x2 wA[15], wB[15];
    #pragma unroll
    for (int j = 0; j < 15; ++j) {
        wA[j] = f16x2{(f16)ra[2 * j], (f16)ra[2 * j + 1]};
        wB[j] = f16x2{(f16)rb[2 * j], (f16)rb[2 * j + 1]};
    }
    const float* sa = Wih + rowA * INP;
    const float* sb = Wih + rowB * INP;
    f16x2 xwA[3], xwB[3];
    #pragma unroll
    for (int j = 0; j < 3; ++j) {
        xwA[j] = f16x2{(f16)sa[2 * j], (f16)sa[2 * j + 1]};
        xwB[j] = f16x2{(f16)sb[2 * j], (f16)sb[2 * j + 1]};
    }
    float bA = 0.f, bB = 0.f;
    if (act) {
        bA = bih[rowA] + bhh[rowA];
        bB = bih[rowB] + bhh[rowB];
    }

    // pin converted weights: pressure now fits, pin only has to block remat
    #pragma unroll
    for (int j = 0; j < 15; ++j) asm("" : "+v"(wA[j]), "+v"(wB[j]));
    #pragma unroll
    for (int j = 0; j < 3; ++j)  asm("" : "+v"(xwA[j]), "+v"(xwB[j]));
    asm("" : "+v"(bA), "+v"(bB));

    // branchless per-half nonlinearity constants:
    //   half0: nA = sigm(aA);  half1: nA = tanh(aA) = 2*sigm(2aA)-1
    const float mA = half ? -LOG2E2 : -LOG2E;
    const float sA = half ? 2.0f : 1.0f;
    const float cA = half ? -1.0f : 0.0f;

    float c = 0.f, h = 0.f;

    // x: wave-uniform 24B, per-lane VMEM loads (one fetch per wave)
    f32x2 xc0, xc1, xc2, xn0, xn1, xn2;
    {
        const f32x2* p = (const f32x2*)(X + (size_t)b * INP);   // t = 0
        xc0 = p[0]; xc1 = p[1]; xc2 = p[2];
    }
    asm volatile("s_waitcnt lgkmcnt(0)" ::: "memory");   // h_sh init visible

    const uint4* hq = (const uint4*)(&h_sh[e][0]);   // 32 halves = 4 x b128

    for (int t = 0; t < SEQ; ++t) {
        // prefetch x for t+1 (VMEM; drained just before use next iter)
        const int tn = (t + 1 < SEQ) ? (t + 1) : (SEQ - 1);
        const f32x2* p = (const f32x2*)(X + ((size_t)tn * BATCH + b) * INP);
        xn0 = p[0]; xn1 = p[1]; xn2 = p[2];

        // h row: 4 x ds_read_b128, broadcast to all lanes
        const uint4 Hq0 = hq[0], Hq1 = hq[1], Hq2 = hq[2], Hq3 = hq[3];
        const f16x2 hp[16] = {
            as_h2(Hq0.x), as_h2(Hq0.y), as_h2(Hq0.z), as_h2(Hq0.w),
            as_h2(Hq1.x), as_h2(Hq1.y), as_h2(Hq1.z), as_h2(Hq1.w),
            as_h2(Hq2.x), as_h2(Hq2.y), as_h2(Hq2.z), as_h2(Hq2.w),
            as_h2(Hq3.x), as_h2(Hq3.y), as_h2(Hq3.z), as_h2(Hq3.w)
        };

        // two f32 accumulation chains per gate row
        float aAe = bA, aAo = 0.f, aBe = bB, aBo = 0.f;
        #define DOT(J, E) do {                                            \
            aA##E = __builtin_amdgcn_fdot2(wA[J], hp[J], aA##E, false);   \
            aB##E = __builtin_amdgcn_fdot2(wB[J], hp[J], aB##E, false);   \
        } while (0)
        DOT(0, e);  DOT(1, o);  DOT(2, e);  DOT(3, o);
        DOT(4, e);  DOT(5, o);  DOT(6, e);  DOT(7, o);
        DOT(8, e);  DOT(9, o);  DOT(10, e); DOT(11, o);
        DOT(12, e); DOT(13, o); DOT(14, e);
        #undef DOT
        // input projection (x converted per step, shared by both rows)
        const f16x2 xh0 = __builtin_amdgcn_cvt_pkrtz(xc0.x, xc0.y);
        const f16x2 xh1 = __builtin_amdgcn_cvt_pkrtz(xc1.x, xc1.y);
        const f16x2 xh2 = __builtin_amdgcn_cvt_pkrtz(xc2.x, xc2.y);
        aAo = __builtin_amdgcn_fdot2(xwA[0], xh0, aAo, false);
        aBo = __builtin_amdgcn_fdot2(xwB[0], xh0, aBo, false);
        aAe = __builtin_amdgcn_fdot2(xwA[1], xh1, aAe, false);
        aBe = __builtin_amdgcn_fdot2(xwB[1], xh1, aBe, false);
        aAo = __builtin_amdgcn_fdot2(xwA[2], xh2, aAo, false);
        aBo = __builtin_amdgcn_fdot2(xwB[2], xh2, aBo, false);

        const float aA = aAe + aAo;
        const float aB = aBe + aBo;

        // half0: nA=sigm_i, nB=sigm_f ; half1: nA=tanh_g, nB=sigm_o
        const float nA = fmaf(sA, rcp_(1.0f + exp2_(mA * aA)), cA);
        const float nB = rcp_(1.0f + exp2_(-LOG2E * aB));

        const float vA = __shfl_xor(nA, 32);
        const float vB = __shfl_xor(nB, 32);

        const float F = half ? vB : nB;   // sigm_f
        const float O = half ? nB : vB;   // sigm_o
        c = fmaf(F, c, nA * vA);          // nA*vA == sigm_i * tanh_g on both halves
        const float tc = 1.0f - 2.0f * rcp_(exp2_(LOG2E2 * c) + 1.0f);
        h = O * tc;

        if (lane < HID) h_sh[e][lane] = (f16)h;   // low half writes (RTN)
        asm volatile("s_waitcnt lgkmcnt(0)" ::: "memory");

        xc0 = xn0; xc1 = xn1; xc2 = xn2;
    }

    // ---- FC1 (lanes 0..29): o1[u] = b1[u] + sum_k W1[u,k] * h[k] ----
    if (lane < HID) {
        float a1 = b1[lane];
        const float* w1r = W1 + lane * HID;
        #pragma unroll
        for (int k = 0; k < HID; ++k) a1 = fmaf(w1r[k], (float)h_sh[e][k], a1);
        o1_sh[e][lane] = a1;
    }
    asm volatile("s_waitcnt lgkmcnt(0)" ::: "memory");

    // ---- FC2 (lanes 0..60): out[o] = b2[o] + sum_j W2[o,j] * o1[j] ----
    if (lane < NOUT) {
        float a2 = b2[lane];
        const float* w2r = W2 + lane * HID;
        #pragma unroll
        for (int k = 0; k < HID; ++k) a2 = fmaf(w2r[k], o1_sh[e][k], a2);
        out[(size_t)b * NOUT + lane] = a2;
    }
}

extern "C" void kernel_launch(void* const* d_in, const int* in_sizes, int n_in,
                              void* d_out, int out_size, void* d_ws, size_t ws_size,
                              hipStream_t stream) {
    const float* X   = (const float*)d_in[0];
    const float* Wih = (const float*)d_in[1];
    const float* Whh = (const float*)d_in[2];
    const float* bih = (const float*)d_in[3];
    const float* bhh = (const float*)d_in[4];
    const float* W1  = (const float*)d_in[5];
    const float* b1  = (const float*)d_in[6];
    const float* W2  = (const float*)d_in[7];
    const float* b2  = (const float*)d_in[8];
    float* out = (float*)d_out;

    dim3 grid(BATCH / WPB);   // 2048 blocks x 2 waves -> 4 waves/SIMD
    dim3 block(64 * WPB);
    hipLaunchKernelGGL(lstm_fused6, grid, block, 0, stream,
                       X, Wih, Whh, bih, bhh, W1, b1, W2, b2, out);
}